// Round 17
// baseline (223.991 us; speedup 1.0000x reference)
//
#include <hip/hip_runtime.h>
#include <hip/hip_bf16.h>
#include <cstdint>

// Problem constants
#define CIN   256
#define COUT  256
#define NB    8
#define NT    16
#define NH    28
#define NW    28
#define HP    30
#define WP    30

#define XM_ELEMS   ((size_t)NB * NT * HP * WP * CIN)   // 29,491,200 bf16
#define XM_BYTES   (XM_ELEMS * 2)

typedef __bf16 bf16x8 __attribute__((ext_vector_type(8)));
typedef float  f32x4  __attribute__((ext_vector_type(4)));

#define AS1 __attribute__((address_space(1)))
#define AS3 __attribute__((address_space(3)))

static __device__ __forceinline__ unsigned short f2bf(float f) {
    __hip_bfloat16 h = __float2bfloat16(f);
    return __builtin_bit_cast(unsigned short, h);
}

// ---------------------------------------------------------------------------
// Pass 1: xm[b][t][hp][wp][ci] = bf16(x[b][ci][t][h][w] * alpha[b][ci][t])
// ---------------------------------------------------------------------------
__global__ void modulate_kernel(const float* __restrict__ x,
                                const float* __restrict__ alpha,
                                unsigned short* __restrict__ xm) {
    const int ci = threadIdx.x;
    const int blk = blockIdx.x;
    const int hp = blk % 30;
    const int bt = blk / 30;
    unsigned short* row = xm + (size_t)(bt * 900 + hp * 30) * 256;
    if (hp == 0 || hp == 29) {
        #pragma unroll
        for (int wp = 0; wp < 30; ++wp) row[wp * 256 + ci] = 0;
        return;
    }
    const int t = bt & 15, b = bt >> 4;
    const int h = hp - 1;
    const float a = alpha[(b * CIN + ci) * NT + t];
    const float* xrow = x + ((size_t)((b * CIN + ci) * NT + t) * NH + h) * NW;
    row[ci] = 0;
    row[29 * 256 + ci] = 0;
    const float4* xv = (const float4*)xrow;
    #pragma unroll
    for (int q = 0; q < 7; ++q) {
        float4 v = xv[q];
        row[(q * 4 + 1) * 256 + ci] = f2bf(v.x * a);
        row[(q * 4 + 2) * 256 + ci] = f2bf(v.y * a);
        row[(q * 4 + 3) * 256 + ci] = f2bf(v.z * a);
        row[(q * 4 + 4) * 256 + ci] = f2bf(v.w * a);
    }
}

// ---------------------------------------------------------------------------
// Pass 2: wB[tap][co][ci] = bf16(weight[co][ci][tap])
// ---------------------------------------------------------------------------
__global__ void repack_w_kernel(const float* __restrict__ w,
                                unsigned short* __restrict__ wB) {
    const int ci = threadIdx.x;
    const int tap = blockIdx.x >> 8;
    const int co  = blockIdx.x & 255;
    wB[((tap * 256 + co) * 256) + ci] = f2bf(w[(co * 256 + ci) * 9 + tap]);
}

// ---------------------------------------------------------------------------
// Pass 3: R15 schedule with A DIRECT L2->REGISTER (no A LDS), B-only
// 4-deep LDS staging. fa(j+2) issued at body j (after MFMA, into the
// just-freed dual set) -> ~2-body (~4000cy) lead fixes R11's latency
// failure. Per-CU per-body LDS-port work 116KB -> 68KB. Steady per-wave
// vmem queue [B(j+2)2, fa(j)4, B(j+3)2, fa(j+1)4]=12; VMW(6) drains
// B(j+2)+fa(j). Mixed-BN grid (64x224 + 448x192), tap-inner K, 64B rows
// with slot^=(row>>1)&3 swizzle, pre-swizzled global_load_lds B source.
// LDS 64KB = 4 x 16KB B. grid=512, block=512 (8 waves 4Mx2N).
// ---------------------------------------------------------------------------

#define BAR()    __builtin_amdgcn_s_barrier()
#define LGKM0()  asm volatile("s_waitcnt lgkmcnt(0)" ::: "memory")
#define VMW(N)   asm volatile("s_waitcnt vmcnt(" #N ")" ::: "memory")
#define SCHED0() __builtin_amdgcn_sched_barrier(0)

// stage B-tile (tapS,cicS) into buf P (0..3): 256(BN+dup)x32, 2 loads/wave
#define STAGE_B(P) do {                                                       \
    const int kh2 = (tapS * 11) >> 5;                                         \
    const int kw2 = tapS - 3 * kh2;                                           \
    const int bOff = ((kh2 - 1) * 30 + (kw2 - 1)) * 256 + cicS * 32;          \
    _Pragma("unroll") for (int c_ = 0; c_ < 2; ++c_)                          \
        __builtin_amdgcn_global_load_lds(                                     \
            (const AS1 void*)(bL[c_] + bOff),                                 \
            (AS3 void*)(lds + (P)*16384 + (c_*128 + wave*16)*64 + lane*16),   \
            16, 0, 0);                                                        \
    if (++tapS == 9) { tapS = 0; ++cicS; }                                    \
} while (0)

// load A fragments for kt (tapA,cicA) straight to registers (L2-resident wB)
#define LOADA(S) do {                                                         \
    const unsigned short* ap_ = aRow + tapA * 65536 + cicA * 32;              \
    _Pragma("unroll") for (int m_ = 0; m_ < 4; ++m_)                          \
        fa##S[m_] = *(const bf16x8*)(ap_ + m_ * 4096);                        \
    if (++tapA == 9) { tapA = 0; ++cicA; }                                    \
} while (0)

#define READF_B(S, P) do {                                                    \
    _Pragma("unroll") for (int f_ = 0; f_ < NF; ++f_)                         \
        fb##S[f_] = *(const bf16x8*)(lds + (P)*16384 +                        \
            (wn*(NF*16) + f_*16 + l15)*64 + readSwz);                         \
} while (0)

#define MFMA_T(S) do {                                                        \
    _Pragma("unroll") for (int m_ = 0; m_ < 4; ++m_)                          \
    _Pragma("unroll") for (int f_ = 0; f_ < NF; ++f_)                         \
        acc[m_][f_] = __builtin_amdgcn_mfma_f32_16x16x32_bf16(                \
            fb##S[f_], fa##S[m_], acc[m_][f_], 0, 0, 0);                      \
} while (0)

// full body j: CS = set j%2, NS = other; read fb(j+1) from NBUF=(j+1)%4;
// stage B(j+4) -> SBUF=j%4; after MFMA issue fa(j+2) into CS set.
#define BODY_F(CS, NS, NBUF, SBUF) do {                                       \
    VMW(6);                                                                   \
    SCHED0();                                                                 \
    BAR();                                                                    \
    READF_B(NS, NBUF);                                                        \
    STAGE_B(SBUF);                                                            \
    SCHED0();                                                                 \
    MFMA_T(CS);                                                               \
    LOADA(CS);                                                                \
    LGKM0();                                                                  \
    SCHED0();                                                                 \
} while (0)

// tail body: no stage; optional LOADA; VMN counted target
#define BODY_T(CS, NS, NBUF, VMN, DO_LOADA) do {                              \
    VMW(VMN);                                                                 \
    SCHED0();                                                                 \
    BAR();                                                                    \
    READF_B(NS, NBUF);                                                        \
    SCHED0();                                                                 \
    MFMA_T(CS);                                                               \
    if (DO_LOADA) LOADA(CS);                                                  \
    LGKM0();                                                                  \
    SCHED0();                                                                 \
} while (0)

template<int NF>
__device__ __forceinline__ void conv_body(
    const unsigned short* __restrict__ xm,
    const unsigned short* __restrict__ wB,
    float* __restrict__ out,
    char* lds, const int n0)
{
    const int tid  = threadIdx.x;
    const int wave = tid >> 6;             // 0..7
    const int lane = tid & 63;
    const int l15  = lane & 15;
    const int wm   = wave >> 1;            // 0..3 co quarter (64)
    const int wn   = wave & 1;             // 0..1 n half (NF*16)
    const int BN   = NF * 32;              // 224 or 192

    // ---- A fragment source (global, L2-resident wB; R11-verified content) ----
    const unsigned short* aRow =
        wB + (wm * 64 + l15) * 256 + (lane >> 4) * 8;

    // ---- B staging sources (pre-swizzled ci slot; inverse of read swizzle) ----
    const int swzE = 8 * ((lane & 3) ^ ((lane >> 3) & 3));
    const unsigned short* bL[2];
    #pragma unroll
    for (int c_ = 0; c_ < 2; ++c_) {
        int nl = c_ * 128 + wave * 16 + (lane >> 2);   // 0..255
        nl = nl > BN - 1 ? BN - 1 : nl;                // pad rows duplicate
        const int n  = n0 + nl;
        const int w_ = n % 28, h_ = (n / 28) % 28, bt = n / 784;
        bL[c_] = xm + (size_t)((bt * 30 + h_ + 1) * 30 + (w_ + 1)) * 256 + swzE;
    }

    // ---- B fragment read base (slot swizzle (row>>1)&3, verified) ----
    const int readSwz = ((lane >> 4) ^ ((l15 >> 1) & 3)) << 4;

    f32x4 acc[4][NF];
    #pragma unroll
    for (int i = 0; i < 4; ++i)
        #pragma unroll
        for (int j = 0; j < NF; ++j) acc[i][j] = f32x4{0.f, 0.f, 0.f, 0.f};

    bf16x8 faA[4], faB[4], fbA[NF], fbB[NF];

    int tapS = 0, cicS = 0;      // B-stage target
    int tapA = 0, cicA = 0;      // fa-load target

    // ---- prologue: B(0..3) -> buf0..3; fa(0)->A, fa(1)->B ----
    STAGE_B(0);
    STAGE_B(1);
    STAGE_B(2);
    STAGE_B(3);
    LOADA(A);                    // fa(0)
    LOADA(B);                    // fa(1)
    VMW(4);                      // drain B0..B3 + fa0; keep fa1
    SCHED0();
    BAR();                       // all waves' B(0) landed
    READF_B(A, 0);               // fb(0)
    LGKM0();
    SCHED0();

    // main: bodies j=0..67, period 4 (buf j%4, set j%2)
    #pragma unroll 1
    for (int it = 0; it < 17; ++it) {
        BODY_F(A, B, 1, 0);      // j=4it+0
        BODY_F(B, A, 2, 1);      // j=4it+1
        BODY_F(A, B, 3, 2);      // j=4it+2
        BODY_F(B, A, 0, 3);      // j=4it+3
    }
    // tail: j=68..70, then peel j=71
    BODY_T(A, B, 1, 6, true);    // j=68: fa(70)
    BODY_T(B, A, 2, 4, true);    // j=69: fa(71)
    BODY_T(A, B, 3, 4, false);   // j=70: reads fb(71)
    VMW(0);                      // fa(71) landed
    SCHED0();
    MFMA_T(B);                   // j=71

    // ---- C-write: lane holds 4 consecutive n (rows) at one co (col) ----
    #pragma unroll
    for (int f = 0; f < NF; ++f) {
        const int n  = n0 + wn * (NF * 16) + f * 16 + ((lane >> 4) << 2);
        const int bt = n / 784;
        const int hw = n - bt * 784;
        const int b = bt >> 4, t = bt & 15;
        float* obase = out + ((size_t)(b * 256) * 16 + t) * 784 + hw;
        #pragma unroll
        for (int m = 0; m < 4; ++m) {
            const int co = wm * 64 + m * 16 + l15;
            *(f32x4*)(obase + (size_t)co * 12544) = acc[m][f];
        }
    }
}

// Mixed grid: bx 0..63 -> BN=224 tiles; bx 64..511 -> BN=192 tiles.
__global__ __launch_bounds__(512, 2) void conv_gemm_kernel(
    const unsigned short* __restrict__ xm,
    const unsigned short* __restrict__ wB,
    float* __restrict__ out) {
    __shared__ __align__(1024) char lds[65536];   // 4 x B 16KB
    const int bx = blockIdx.x;
    if (bx < 64) {
        conv_body<7>(xm, wB, out, lds, bx * 224);
    } else {
        conv_body<6>(xm, wB, out, lds, 14336 + (bx - 64) * 192);
    }
}

// ---------------------------------------------------------------------------
extern "C" void kernel_launch(void* const* d_in, const int* in_sizes, int n_in,
                              void* d_out, int out_size, void* d_ws, size_t ws_size,
                              hipStream_t stream) {
    const float* x      = (const float*)d_in[0];
    const float* alpha  = (const float*)d_in[1];
    const float* weight = (const float*)d_in[2];
    float* out = (float*)d_out;

    unsigned short* xm = (unsigned short*)d_ws;
    unsigned short* wB = (unsigned short*)((char*)d_ws + XM_BYTES);

    modulate_kernel<<<dim3(NB * NT * HP), dim3(256), 0, stream>>>(x, alpha, xm);
    repack_w_kernel<<<dim3(9 * 256), dim3(256), 0, stream>>>(weight, wB);
    conv_gemm_kernel<<<dim3(512), dim3(512), 0, stream>>>(xm, wB, out);
}